// Round 1
// baseline (797.217 us; speedup 1.0000x reference)
//
#include <hip/hip_runtime.h>
#include <math.h>

#define B_ 8
#define N_ 20000
#define K_ 128
#define C_ 256

static_assert(N_ % 32 == 0, "N must be multiple of 32");

constexpr float LMBDA = 100.0f;
constexpr float EPS_EV = 1e-10f;

// ---------------------------------------------------------------------------
// Kernel 1: projection GEMM  out[k,c] = sum_n E[k,n] * F[n,c]
// Tile: TM=64 (k) x TN=128 (c), TK=32, split-K over n into S chunks.
// partial layout: part[(bm*S + s)*K*C + k*C + c], bm = b*2 + mat
// ---------------------------------------------------------------------------
__global__ __launch_bounds__(256)
void proj_gemm(const float* __restrict__ feat_x, const float* __restrict__ feat_y,
               const float* __restrict__ evx, const float* __restrict__ evy,
               float* __restrict__ part, int S, int chunk) {
  const int bm = blockIdx.z;
  const int b = bm >> 1, mat = bm & 1;
  const float* __restrict__ E = (mat ? evy : evx) + (size_t)b * K_ * N_;
  const float* __restrict__ F = (mat ? feat_y : feat_x) + (size_t)b * N_ * C_;
  const int mt = blockIdx.x >> 1, ct = blockIdx.x & 1;
  const int s = blockIdx.y;
  const int k0 = mt * 64, c0 = ct * 128;
  const int nb = s * chunk;
  const int ne = min(N_, nb + chunk);

  __shared__ float Et[32][64];   // [nn][kk] transposed E tile
  __shared__ float Ft[32][128];  // [nn][cc]

  const int t = threadIdx.x;
  const int tr = (t >> 4) << 2;  // 4 rows per thread
  const int tc = (t & 15) << 3;  // 8 cols per thread
  float acc[4][8] = {};

  for (int n0 = nb; n0 < ne; n0 += 32) {
    // load E tile: 64 rows x 32 n  (512 float4, 2/thread)
#pragma unroll
    for (int l = 0; l < 2; ++l) {
      int f = t + (l << 8);
      int kk = f >> 3;
      int nn = (f & 7) << 2;
      const float4 v = *(const float4*)(E + (size_t)(k0 + kk) * N_ + (n0 + nn));
      Et[nn + 0][kk] = v.x; Et[nn + 1][kk] = v.y;
      Et[nn + 2][kk] = v.z; Et[nn + 3][kk] = v.w;
    }
    // load F tile: 32 n x 128 c (1024 float4, 4/thread)
#pragma unroll
    for (int l = 0; l < 4; ++l) {
      int f = t + (l << 8);
      int nn = f >> 5;
      int cc = (f & 31) << 2;
      *(float4*)&Ft[nn][cc] = *(const float4*)(F + (size_t)(n0 + nn) * C_ + (c0 + cc));
    }
    __syncthreads();
#pragma unroll
    for (int nn = 0; nn < 32; ++nn) {
      const float4 a4 = *(const float4*)&Et[nn][tr];
      const float4 b4 = *(const float4*)&Ft[nn][tc];
      const float4 b5 = *(const float4*)&Ft[nn][tc + 4];
      const float av[4] = {a4.x, a4.y, a4.z, a4.w};
      const float bv[8] = {b4.x, b4.y, b4.z, b4.w, b5.x, b5.y, b5.z, b5.w};
#pragma unroll
      for (int i = 0; i < 4; ++i)
#pragma unroll
        for (int j = 0; j < 8; ++j)
          acc[i][j] = fmaf(av[i], bv[j], acc[i][j]);
    }
    __syncthreads();
  }

  float* __restrict__ P = part + ((size_t)bm * S + s) * (K_ * C_);
#pragma unroll
  for (int i = 0; i < 4; ++i) {
    float4 o0 = {acc[i][0], acc[i][1], acc[i][2], acc[i][3]};
    float4 o1 = {acc[i][4], acc[i][5], acc[i][6], acc[i][7]};
    *(float4*)(P + (size_t)(k0 + tr + i) * C_ + (c0 + tc)) = o0;
    *(float4*)(P + (size_t)(k0 + tr + i) * C_ + (c0 + tc + 4)) = o1;
  }
}

// ---------------------------------------------------------------------------
// Kernel 2: reduce split-K partials -> AB[(b*2+mat)*K*C + ...]
// ---------------------------------------------------------------------------
__global__ void reduce_parts(const float* __restrict__ part, float* __restrict__ AB, int S) {
  int idx = blockIdx.x * 256 + threadIdx.x;
  if (idx >= 16 * K_ * C_) return;
  int bm = idx / (K_ * C_);
  int rem = idx - bm * (K_ * C_);
  float v = 0.f;
  for (int s = 0; s < S; ++s) v += part[((size_t)bm * S + s) * (K_ * C_) + rem];
  AB[idx] = v;
}

// ---------------------------------------------------------------------------
// Kernel 3: gram matrices.  which=0: Sm = A A^T + 1e-8 I ; which=1: Rm = Bm A^T
// one block per (b, which); 256 threads, 8x8 outputs/thread, operands L2-hot
// ---------------------------------------------------------------------------
__global__ __launch_bounds__(256)
void gram_kernel(const float* __restrict__ AB, float* __restrict__ Sm, float* __restrict__ Rm) {
  const int b = blockIdx.x, which = blockIdx.y;
  const float* __restrict__ L  = AB + ((size_t)(b * 2 + which)) * (K_ * C_);
  const float* __restrict__ Ar = AB + ((size_t)(b * 2)) * (K_ * C_);
  float* __restrict__ out = (which ? Rm : Sm) + (size_t)b * (K_ * K_);
  const int t = threadIdx.x;
  const int ir = (t >> 4) << 3, jc = (t & 15) << 3;
  float acc[8][8] = {};
  for (int c0 = 0; c0 < C_; c0 += 4) {
    float4 li[8], rj[8];
#pragma unroll
    for (int i = 0; i < 8; ++i) li[i] = *(const float4*)(L + (size_t)(ir + i) * C_ + c0);
#pragma unroll
    for (int j = 0; j < 8; ++j) rj[j] = *(const float4*)(Ar + (size_t)(jc + j) * C_ + c0);
#pragma unroll
    for (int i = 0; i < 8; ++i)
#pragma unroll
      for (int j = 0; j < 8; ++j)
        acc[i][j] += li[i].x * rj[j].x + li[i].y * rj[j].y +
                     li[i].z * rj[j].z + li[i].w * rj[j].w;
  }
#pragma unroll
  for (int i = 0; i < 8; ++i)
#pragma unroll
    for (int j = 0; j < 8; ++j) {
      float v = acc[i][j];
      if (!which && (ir + i) == (jc + j)) v += 1e-8f;
      out[(size_t)(ir + i) * K_ + (jc + j)] = v;
    }
}

// ---------------------------------------------------------------------------
// Kernel 4: mask preparation. Per batch: q1,p1 (from evals_x, col idx),
// q2,p2 (from evals_y, row idx). PQ[b*512 + {0,128,256,384} + k]
// ---------------------------------------------------------------------------
__global__ void mask_prep(const float* __restrict__ evx, const float* __restrict__ evy,
                          float* __restrict__ PQ) {
  const int b = blockIdx.x, t = threadIdx.x;  // 128 threads
  float e1 = evx[b * K_ + t];
  float e2 = evy[b * K_ + t];
  if (e1 != e1) e1 = EPS_EV;
  if (e2 != e2) e2 = EPS_EV;
  e1 = fminf(fmaxf(e1, EPS_EV), 1e6f);
  e2 = fminf(fmaxf(e2, EPS_EV), 1e6f);

  // block-wide max of max(e1,e2): 2 waves
  __shared__ float wmax[2];
  float v = fmaxf(e1, e2);
#pragma unroll
  for (int d = 1; d < 64; d <<= 1) v = fmaxf(v, __shfl_xor(v, d, 64));
  if ((t & 63) == 0) wmax[t >> 6] = v;
  __syncthreads();
  const float scale = fmaxf(fmaxf(wmax[0], wmax[1]), 1e-10f);

  const float g1 = sqrtf(e1 / scale);   // gamma = 0.5
  const float g2 = sqrtf(e2 / scale);
  const float d1 = fmaf(g1, g1, 1.f);
  const float d2 = fmaf(g2, g2, 1.f);
  float* P = PQ + b * 512;
  P[t]       = g1 / d1;  // q1 (col)
  P[128 + t] = 1.f / d1; // p1
  P[256 + t] = g2 / d2;  // q2 (row)
  P[384 + t] = 1.f / d2; // p2
}

// ---------------------------------------------------------------------------
// Kernel 5: in-place Gauss-Jordan inverse of S (SPD, no pivoting), in LDS.
// 8 blocks (one per batch), 256 threads, row-stride 132 to spread banks.
// ---------------------------------------------------------------------------
__global__ __launch_bounds__(256)
void gj_inverse(const float* __restrict__ Sm, float* __restrict__ Sinv) {
  const int b = blockIdx.x, t = threadIdx.x;
  __shared__ float a[K_ * 132];
  __shared__ float rowk[K_], colk[K_];
  __shared__ float pvs;
  const float* __restrict__ Sb = Sm + (size_t)b * (K_ * K_);
#pragma unroll
  for (int l = 0; l < 16; ++l) {
    int f = t + (l << 8);
    int i = f >> 5, j = (f & 31) << 2;
    *(float4*)&a[i * 132 + j] = *(const float4*)(Sb + i * K_ + j);
  }
  __syncthreads();
  const int j4 = (t & 31) << 2;
  const int r0 = t >> 5;
  for (int k = 0; k < K_; ++k) {
    if (t < K_) rowk[t] = a[k * 132 + t];
    else        colk[t - K_] = a[(t - K_) * 132 + k];
    if (t == 0) pvs = 1.0f / a[k * 132 + k];
    __syncthreads();
    const float p = pvs;
    const bool jhit = (k >= j4) && (k < j4 + 4);
    const float rp0 = rowk[j4 + 0] * p, rp1 = rowk[j4 + 1] * p;
    const float rp2 = rowk[j4 + 2] * p, rp3 = rowk[j4 + 3] * p;
#pragma unroll
    for (int l = 0; l < 16; ++l) {
      const int i = r0 + (l << 3);
      float4 v = *(float4*)&a[i * 132 + j4];
      if (i == k) {
        v.x = rp0; v.y = rp1; v.z = rp2; v.w = rp3;
        if (jhit) ((float*)&v)[k - j4] = p;
      } else {
        const float ci = colk[i];
        v.x = fmaf(-ci, rp0, v.x);
        v.y = fmaf(-ci, rp1, v.y);
        v.z = fmaf(-ci, rp2, v.z);
        v.w = fmaf(-ci, rp3, v.w);
        if (jhit) ((float*)&v)[k - j4] = -ci * p;
      }
      *(float4*)&a[i * 132 + j4] = v;
    }
    __syncthreads();
  }
  float* __restrict__ O = Sinv + (size_t)b * (K_ * K_);
#pragma unroll
  for (int l = 0; l < 16; ++l) {
    int f = t + (l << 8);
    int i = f >> 5, j = (f & 31) << 2;
    *(float4*)(O + i * K_ + j) = *(const float4*)&a[i * 132 + j];
  }
}

// ---------------------------------------------------------------------------
// Kernel 6: one Neumann iteration.  Xout = (R - W .* Xin) @ Sinv
// W[i,k] = LMBDA * ((q2[i]-q1[k])^2 + (p2[i]-p1[k])^2).  first=1 -> T = R.
// One block per batch; 128x128 output, 8x8 per thread, K-chunks of 32.
// ---------------------------------------------------------------------------
__global__ __launch_bounds__(256)
void solve_iter(const float* __restrict__ Rm, const float* __restrict__ Sinv,
                const float* __restrict__ PQ, const float* __restrict__ Xin,
                float* __restrict__ Xout, const int first) {
  const int b = blockIdx.x, t = threadIdx.x;
  __shared__ float Tt[32][128];  // [kk][i]
  __shared__ float Sv[32][128];  // [kk][j]
  __shared__ float q1[K_], p1[K_], q2[K_], p2[K_];
  if (t < K_) {
    const float* P = PQ + b * 512;
    q1[t] = P[t]; p1[t] = P[128 + t]; q2[t] = P[256 + t]; p2[t] = P[384 + t];
  }
  __syncthreads();
  const float* __restrict__ Rb = Rm + (size_t)b * (K_ * K_);
  const float* __restrict__ Xb = Xin + (size_t)b * (K_ * K_);
  const float* __restrict__ Si = Sinv + (size_t)b * (K_ * K_);
  const int ir = (t >> 4) << 3, jc = (t & 15) << 3;
  float acc[8][8] = {};

  for (int k0 = 0; k0 < K_; k0 += 32) {
    // stage T chunk transposed: rows i (all 128), cols k0..k0+31
#pragma unroll
    for (int l = 0; l < 4; ++l) {
      int f = t + (l << 8);
      int i = f >> 3;
      int kk = (f & 7) << 2;
      const int k = k0 + kk;
      float4 tv = *(const float4*)(Rb + (size_t)i * K_ + k);
      if (!first) {
        const float4 x4 = *(const float4*)(Xb + (size_t)i * K_ + k);
        const float qi = q2[i], pi = p2[i];
        float dq, dp, w;
        dq = qi - q1[k + 0]; dp = pi - p1[k + 0]; w = fmaf(dq, dq, dp * dp);
        tv.x = fmaf(-LMBDA * w, x4.x, tv.x);
        dq = qi - q1[k + 1]; dp = pi - p1[k + 1]; w = fmaf(dq, dq, dp * dp);
        tv.y = fmaf(-LMBDA * w, x4.y, tv.y);
        dq = qi - q1[k + 2]; dp = pi - p1[k + 2]; w = fmaf(dq, dq, dp * dp);
        tv.z = fmaf(-LMBDA * w, x4.z, tv.z);
        dq = qi - q1[k + 3]; dp = pi - p1[k + 3]; w = fmaf(dq, dq, dp * dp);
        tv.w = fmaf(-LMBDA * w, x4.w, tv.w);
      }
      Tt[kk + 0][i] = tv.x; Tt[kk + 1][i] = tv.y;
      Tt[kk + 2][i] = tv.z; Tt[kk + 3][i] = tv.w;
    }
    // stage Sinv chunk: rows k0..k0+31 (contiguous)
#pragma unroll
    for (int l = 0; l < 4; ++l) {
      int f = t + (l << 8);
      int kk = f >> 5, j = (f & 31) << 2;
      *(float4*)&Sv[kk][j] = *(const float4*)(Si + (size_t)(k0 + kk) * K_ + j);
    }
    __syncthreads();
#pragma unroll
    for (int kk = 0; kk < 32; ++kk) {
      const float4 a0 = *(const float4*)&Tt[kk][ir];
      const float4 a1 = *(const float4*)&Tt[kk][ir + 4];
      const float4 b0 = *(const float4*)&Sv[kk][jc];
      const float4 b1 = *(const float4*)&Sv[kk][jc + 4];
      const float av[8] = {a0.x, a0.y, a0.z, a0.w, a1.x, a1.y, a1.z, a1.w};
      const float bv[8] = {b0.x, b0.y, b0.z, b0.w, b1.x, b1.y, b1.z, b1.w};
#pragma unroll
      for (int i = 0; i < 8; ++i)
#pragma unroll
        for (int j = 0; j < 8; ++j)
          acc[i][j] = fmaf(av[i], bv[j], acc[i][j]);
    }
    __syncthreads();
  }

  float* __restrict__ O = Xout + (size_t)b * (K_ * K_);
#pragma unroll
  for (int i = 0; i < 8; ++i) {
    float4 o0 = {acc[i][0], acc[i][1], acc[i][2], acc[i][3]};
    float4 o1 = {acc[i][4], acc[i][5], acc[i][6], acc[i][7]};
    *(float4*)(O + (size_t)(ir + i) * K_ + jc) = o0;
    *(float4*)(O + (size_t)(ir + i) * K_ + jc + 4) = o1;
  }
}

// ---------------------------------------------------------------------------
extern "C" void kernel_launch(void* const* d_in, const int* in_sizes, int n_in,
                              void* d_out, int out_size, void* d_ws, size_t ws_size,
                              hipStream_t stream) {
  (void)in_sizes; (void)n_in; (void)out_size;
  const float* feat_x  = (const float*)d_in[0];
  const float* feat_y  = (const float*)d_in[1];
  const float* evals_x = (const float*)d_in[2];
  const float* evals_y = (const float*)d_in[3];
  const float* evtx    = (const float*)d_in[4];
  const float* evty    = (const float*)d_in[5];
  float* out = (float*)d_out;
  float* ws  = (float*)d_ws;

  // workspace sizing (floats)
  const size_t KC16 = (size_t)16 * K_ * C_;            // 524288 (AB / one split slab)
  const size_t KK   = (size_t)K_ * K_;                 // 16384
  const size_t fixed = KC16 + 3 * (KK * B_) + 4096 + 2 * (KK * B_);
  int S = 8;
  while (S > 1 && ((size_t)S * KC16 + fixed) * sizeof(float) > ws_size) S >>= 1;

  float* part = ws;
  float* AB   = part + (size_t)S * KC16;
  float* Sm   = AB + KC16;
  float* Rm   = Sm + KK * B_;
  float* Sinv = Rm + KK * B_;
  float* PQ   = Sinv + KK * B_;
  float* X0   = PQ + 4096;
  float* X1   = X0 + KK * B_;

  const int tiles = (N_ / 32 + S - 1) / S;
  const int chunk = tiles * 32;

  proj_gemm<<<dim3(4, S, 16), 256, 0, stream>>>(feat_x, feat_y, evtx, evty, part, S, chunk);
  reduce_parts<<<dim3((16 * K_ * C_ + 255) / 256), 256, 0, stream>>>(part, AB, S);
  gram_kernel<<<dim3(8, 2), 256, 0, stream>>>(AB, Sm, Rm);
  mask_prep<<<dim3(8), 128, 0, stream>>>(evals_x, evals_y, PQ);
  gj_inverse<<<dim3(8), 256, 0, stream>>>(Sm, Sinv);
  solve_iter<<<dim3(8), 256, 0, stream>>>(Rm, Sinv, PQ, X0, X0, 1);
  solve_iter<<<dim3(8), 256, 0, stream>>>(Rm, Sinv, PQ, X0, X1, 0);
  solve_iter<<<dim3(8), 256, 0, stream>>>(Rm, Sinv, PQ, X1, out, 0);
}